// Round 10
// baseline (227.334 us; speedup 1.0000x reference)
//
#include <hip/hip_runtime.h>
#include <hip/hip_bf16.h>

// CrossAttentionFusion: B=4, C=Cs=256, CI=128, H=W=64 -> N=M=4096
// R16 = QBLK=64 attn (traffic halving):
//  - Invariant R8..R15: attn ~106-113us under every sync structure => not
//    pipeline-bound. Traffic model: 512 blocks x 3MB (full K+V per batch) =
//    1.5GB @ ~14TB/s effective L2/L3 = the 107us floor. Per-XCD working set
//    6MB thrashes 4MB L2. Per-SIMD issue only ~18% busy.
//  - R16: one block serves TWO q-tiles (64 q) on one K/V read stream:
//    256 blocks x 3MB = 768MB. V regs reused for PV_A+PV_B; K frag loads
//    shared by QK_A/QK_B (two independent MFMA chains = in-wave ILP).
//    Both Q tiles in LDS (16KB) -> ~235 VGPR, launch_bounds(256,1).
//    R13 counted-vmcnt kbuf[3] K-DMA pipeline kept verbatim.
//  - wprep/projfused unchanged from R15 (fusion kept: -10us measured).
//
// qk-frag (Q B-op / K A-op), per 32-row group g:
//   addr = g*4096 + (ch>>4)*512 + ((ch>>3)&1)*256 + row*8 + (ch&7)
//   (K rows permuted: row = l32^12 if (l32>>2)&3 in {1,2} -> shuffle-free PV)
// V-frag (PV A-op), per 32-key group g: addr = g*8192 + (ch>>5)*1024
//   + ((key>>4)&1)*512 + ((key>>3)&1)*256 + (ch&31)*8 + (key&7)

typedef __bf16  bf16x8  __attribute__((ext_vector_type(8)));
typedef float   f32x16  __attribute__((ext_vector_type(16)));

#define LOG2E 1.4426950408889634f

union BF8 { __hip_bfloat162 h[4]; bf16x8 v; };
union U4  { unsigned u[4]; bf16x8 v; };

__device__ inline bf16x8 pack8(const float f[8]) {
  BF8 u;
#pragma unroll
  for (int i = 0; i < 4; i++)
    u.h[i] = __float22bfloat162_rn(float2{f[2 * i], f[2 * i + 1]});
  return u.v;
}

__device__ inline void dma16(const void* g, void* l) {
  __builtin_amdgcn_global_load_lds(
      (const __attribute__((address_space(1))) unsigned int*)g,
      (__attribute__((address_space(3))) unsigned int*)l, 16, 0, 0);
}

// ---------------------------------------------------------------------------
// wprep: W -> W-frag bf16 (16 blocks).  (unchanged from R15)
// ---------------------------------------------------------------------------
__global__ __launch_bounds__(256) void wprep_kernel(
    const float* __restrict__ Wq, const float* __restrict__ Wk,
    const float* __restrict__ Wv, __hip_bfloat16* __restrict__ wfr)
{
  const int base = blockIdx.x * 1024;
  const int tid = threadIdx.x;
#pragma unroll
  for (int i = 0; i < 4; i++) {
    int c = base + i * 256 + tid;          // [0, 16384)
    const float* Ws; __hip_bfloat16* dst; int rc;
    if (c < 4096)      { Ws = Wq; dst = wfr;          rc = c; }
    else if (c < 8192) { Ws = Wk; dst = wfr + 32768;  rc = c - 4096; }
    else               { Ws = Wv; dst = wfr + 65536;  rc = c - 8192; }
    int ot = rc >> 10, cs = (rc >> 6) & 15, rem = rc & 63;
    int hf = rem >> 5, l32 = rem & 31;
    const float* src = Ws + (ot * 32 + l32) * 256 + cs * 16 + hf * 8;
    float f[8];
#pragma unroll
    for (int j = 0; j < 8; j++) f[j] = src[j];
    *(bf16x8*)(dst + ot * 8192 + cs * 512 + hf * 256 + l32 * 8) = pack8(f);
  }
}

// ---------------------------------------------------------------------------
// projfused: stage input tile via LDS, pack to frag-LDS, MFMA from LDS,
// direct scatter stores. Grid 512: [0,256) q(x), [256,512) kv(z).
// (unchanged from R15)
// ---------------------------------------------------------------------------
struct PFSmem {
  float stg[128 * 68];
  alignas(16) __hip_bfloat16 frag[16384];
};

__global__ __launch_bounds__(512, 2) void projfused(
    const float* __restrict__ x, const float* __restrict__ z,
    const __hip_bfloat16* __restrict__ wfr,
    const float* __restrict__ bq, const float* __restrict__ bk,
    const float* __restrict__ bv,
    __hip_bfloat16* __restrict__ qp, __hip_bfloat16* __restrict__ kp,
    __hip_bfloat16* __restrict__ vp)
{
  __shared__ PFSmem sm;
  const int bi = blockIdx.x;
  const bool qmode = bi < 256;
  const int j2 = qmode ? bi : bi - 256;
  const int b = j2 >> 6, pc = j2 & 63;
  const float* in = qmode ? x : z;
  const size_t ib = (size_t)b * 256 * 4096 + pc * 64;

  const int tid = threadIdx.x, w = tid >> 6, lane = tid & 63,
            l32 = lane & 31, half = lane >> 5;
  const int pix4 = (tid & 15) * 4;

#pragma unroll
  for (int it = 0; it < 4; it++) {
    int ch = it * 32 + (tid >> 4);
    float4 v4 = *(const float4*)&in[ib + (size_t)ch * 4096 + pix4];
    *(float4*)&sm.stg[ch * 68 + pix4] = v4;
  }
  __syncthreads();
#pragma unroll
  for (int i = 0; i < 2; i++) {
    int c = i * 512 + tid;
    int grp = c >> 9, csl = (c >> 6) & 7, rem = c & 63;
    int hf = rem >> 5, lr = rem & 31;
    int chb = csl * 16 + hf * 8;
    float f[8];
#pragma unroll
    for (int j = 0; j < 8; j++) f[j] = sm.stg[(chb + j) * 68 + grp * 32 + lr];
    *(bf16x8*)(sm.frag + grp * 8192 + csl * 512 + hf * 256 + lr * 8) = pack8(f);
  }
  __syncthreads();

#pragma unroll
  for (int it = 0; it < 4; it++) {
    int ch = it * 32 + (tid >> 4);
    float4 v4 = *(const float4*)&in[ib + (size_t)(128 + ch) * 4096 + pix4];
    *(float4*)&sm.stg[ch * 68 + pix4] = v4;
  }
  __syncthreads();
#pragma unroll
  for (int i = 0; i < 2; i++) {
    int c = i * 512 + tid;
    int grp = c >> 9, csl = (c >> 6) & 7, rem = c & 63;
    int hf = rem >> 5, lr = rem & 31;
    int chb = csl * 16 + hf * 8;
    float f[8];
#pragma unroll
    for (int j = 0; j < 8; j++) f[j] = sm.stg[(chb + j) * 68 + grp * 32 + lr];
    *(bf16x8*)(sm.frag + grp * 8192 + (csl + 8) * 512 + hf * 256 + lr * 8) =
        pack8(f);
  }
  __syncthreads();

  const int t4 = (l32 >> 2) & 3;
  const int kperm = (t4 == 1 || t4 == 2) ? (l32 ^ 12) : l32;

  if (qmode) {
    const int ot = w >> 1, pg = w & 1;
    bf16x8 bfr[16];
#pragma unroll
    for (int cs = 0; cs < 16; cs++)
      bfr[cs] = *(const bf16x8*)(sm.frag + pg * 8192 + cs * 512 + lane * 8);
    const __hip_bfloat16* wp = wfr + ot * 8192 + lane * 8;
    bf16x8 wfg[16];
#pragma unroll
    for (int cs = 0; cs < 16; cs++) wfg[cs] = *(const bf16x8*)(wp + cs * 512);
    float bb[16];
#pragma unroll
    for (int r = 0; r < 16; r++)
      bb[r] = bq[ot * 32 + (r & 3) + 8 * (r >> 2) + 4 * half];
    f32x16 O = {};
#pragma unroll
    for (int cs = 0; cs < 16; cs++)
      O = __builtin_amdgcn_mfma_f32_32x32x16_bf16(wfg[cs], bfr[cs], O, 0, 0, 0);
    __hip_bfloat16* qb = qp + ((size_t)(b * 128 + pc * 2 + pg)) * 4096;
#pragma unroll
    for (int r = 0; r < 16; r++) {
      int oc = ot * 32 + (r & 3) + 8 * (r >> 2) + 4 * half;
      qb[(oc >> 4) * 512 + ((oc >> 3) & 1) * 256 + l32 * 8 + (oc & 7)] =
          __float2bfloat16((O[r] + bb[r]) * LOG2E);
    }
  } else {
    const int pg = w & 1;
    bf16x8 bfr[16];
#pragma unroll
    for (int cs = 0; cs < 16; cs++)
      bfr[cs] = *(const bf16x8*)(sm.frag + pg * 8192 + cs * 512 + lane * 8);
    const size_t pgg = (size_t)(b * 128 + pc * 2 + pg);
#pragma unroll
    for (int jj = 0; jj < 3; jj++) {
      const int t = (w + jj * 8) >> 1;
      const bool isK = (t < 4);
      const __hip_bfloat16* wp = wfr + (isK ? 32768 + t * 8192
                                            : 65536 + (t - 4) * 8192) + lane * 8;
      bf16x8 wfg[16];
#pragma unroll
      for (int cs = 0; cs < 16; cs++) wfg[cs] = *(const bf16x8*)(wp + cs * 512);
      const float* bias = isK ? bk : bv;
      const int ocb = (isK ? t : t - 4) * 32;
      float bb[16];
#pragma unroll
      for (int r = 0; r < 16; r++)
        bb[r] = bias[ocb + (r & 3) + 8 * (r >> 2) + 4 * half];
      f32x16 O = {};
#pragma unroll
      for (int cs = 0; cs < 16; cs++)
        O = __builtin_amdgcn_mfma_f32_32x32x16_bf16(wfg[cs], bfr[cs], O, 0, 0, 0);
      if (isK) {
        __hip_bfloat16* kb = kp + pgg * 4096;
#pragma unroll
        for (int r = 0; r < 16; r++) {
          int oc = t * 32 + (r & 3) + 8 * (r >> 2) + 4 * half;
          kb[(oc >> 4) * 512 + ((oc >> 3) & 1) * 256 + kperm * 8 + (oc & 7)] =
              __float2bfloat16(O[r] + bb[r]);
        }
      } else {
        __hip_bfloat16* vb = vp + pgg * 8192 + (t - 4) * 1024
            + (l32 >> 4) * 512 + ((l32 >> 3) & 1) * 256 + (l32 & 7);
#pragma unroll
        for (int r = 0; r < 16; r++) {
          int rr = (r & 3) + 8 * (r >> 2) + 4 * half;
          vb[rr * 8] = __float2bfloat16(O[r] + bb[r]);
        }
      }
    }
  }
}

// ---------------------------------------------------------------------------
// attn R16: grid 256 = (b, qt2); QBLK=64 (q-tiles qtA=2*qt2, qtB=qtA+1).
// 4 waves = (kh, chh). R13 counted-vmcnt kbuf[3] K-DMA pipeline; Q in LDS;
// per tile: V loads -> QK_A/QK_B (shared kf, dual chains) -> softmax_A,
// PV_A -> softmax_B, PV_B -> raw s_barrier. V regs reused A+B (traffic /2).
// ---------------------------------------------------------------------------
struct AttnSmem {
  union {
    struct {
      __hip_bfloat16 kbuf[3][8192];   // 48 KiB triple buffer
      __hip_bfloat16 qlds[8192];      // 16 KiB: q-tiles A (0..4095), B (+4096)
    } m;
    float ostage[256][65];            // 66.6 KiB epilogue [ch][q64], pad 65
  } u;
  float redu[4][64];
  float rinv[64];
};

__global__ __launch_bounds__(256, 1) void attn_kernel(
    const __hip_bfloat16* __restrict__ qv, const __hip_bfloat16* __restrict__ kv,
    const __hip_bfloat16* __restrict__ vv,
    const float* __restrict__ x_main, const float* __restrict__ gammap,
    float* __restrict__ out)
{
  __shared__ AttnSmem sm;
  const int i   = blockIdx.x;          // 256 blocks
  const int b   = (i & 7) >> 1;        // XCD-pair -> batch (K+V L2-resident)
  const int qt2 = ((i >> 3) << 1) | (i & 1);   // [0,64) q-group per batch
  const int qtA = qt2 * 2;
  const int n0  = qt2 * 64;
  const int tid = threadIdx.x;
  const int w   = tid >> 6, lane = tid & 63, l32 = lane & 31;
  const int kh  = w >> 1, chh = w & 1;
  const int t0  = qt2 & 63;            // stagger: de-correlate block streams

  // Q (both tiles) -> LDS: 8192 bf16, contiguous in qp layout
  {
    const __hip_bfloat16* qsrc = qv + ((size_t)(b * 128 + qtA)) * 4096;
#pragma unroll
    for (int j = 0; j < 4; j++)
      *(bf16x8*)(sm.u.m.qlds + j * 2048 + tid * 8) =
          *(const bf16x8*)(qsrc + j * 2048 + tid * 8);
  }

  const __hip_bfloat16* kg = kv + (size_t)(b * 128) * 4096;
  const __hip_bfloat16* vg = vv + (size_t)(b * 128) * 8192;

  auto stage = [&](int ta, int par) {
    __hip_bfloat16* kd = sm.u.m.kbuf[par];
    const __hip_bfloat16* ksrc = kg + (size_t)ta * 8192 + lane * 8;
#pragma unroll
    for (int c = 0; c < 4; c++) {
      int ck = w * 4 + c;
      dma16(ksrc + ck * 512, kd + ck * 512 + lane * 8);
    }
  };

  f32x16 OA[4], OB[4];
#pragma unroll
  for (int c = 0; c < 4; c++)
#pragma unroll
    for (int r = 0; r < 16; r++) { OA[c][r] = 0.f; OB[c][r] = 0.f; }

  float lA = 0.f, lB = 0.f;

  auto softmax = [&](const f32x16& S, bf16x8& pf0, bf16x8& pf1, float& lacc) {
    unsigned p2[8];
    float lsub = 0.f;
#pragma unroll
    for (int i2 = 0; i2 < 8; i2++) {
      float a = exp2f(S[2 * i2]     - 64.0f);
      float c = exp2f(S[2 * i2 + 1] - 64.0f);
      lsub += a + c;
      union { __hip_bfloat162 h; unsigned u; } cv;
      cv.h = __float22bfloat162_rn(float2{a, c});
      p2[i2] = cv.u;
    }
    lacc += lsub;
    U4 f0, f1;
    f0.u[0] = p2[0]; f0.u[1] = p2[1]; f0.u[2] = p2[2]; f0.u[3] = p2[3];
    f1.u[0] = p2[4]; f1.u[1] = p2[5]; f1.u[2] = p2[6]; f1.u[3] = p2[7];
    pf0 = f0.v; pf1 = f1.v;
  };

  // ---- prologue: stage t0, t0+1; one-time full drain (also covers qlds) ----
  stage(t0, 0);
  stage((t0 + 1) & 63, 1);
  __syncthreads();

  // ---- main loop: 64 tiles, 1 raw barrier/tile, vmcnt never drained ----
#pragma unroll 1
  for (int lt = 0; lt < 64; ++lt) {
    const int ta = (lt + t0) & 63;

    // V frags FIRST (older than this iter's DMA in the vmcnt FIFO)
    const __hip_bfloat16* vb = vg + (size_t)(ta * 2 + kh) * 8192
                             + chh * 4096 + lane * 8;
    bf16x8 Vc[8];
#pragma unroll
    for (int c = 0; c < 4; c++) {
      Vc[2 * c]     = *(const bf16x8*)(vb + c * 1024);
      Vc[2 * c + 1] = *(const bf16x8*)(vb + c * 1024 + 512);
    }
    __builtin_amdgcn_sched_barrier(0);   // pin V-issue before DMA-issue

    if (lt < 62) stage((lt + 2 + t0) & 63, (lt + 2) % 3);

    // QK_A and QK_B: shared kf load, two independent MFMA chains
    const __hip_bfloat16* kbase = sm.u.m.kbuf[lt % 3] + kh * 4096 + lane * 8;
    const __hip_bfloat16* qab   = sm.u.m.qlds + lane * 8;
    f32x16 SA = {}, SB = {};
#pragma unroll
    for (int cs = 0; cs < 8; cs++) {
      bf16x8 kf = *(const bf16x8*)(kbase + cs * 512);
      bf16x8 qa = *(const bf16x8*)(qab + cs * 512);
      bf16x8 qb2 = *(const bf16x8*)(qab + 4096 + cs * 512);
      SA = __builtin_amdgcn_mfma_f32_32x32x16_bf16(kf, qa,  SA, 0, 0, 0);
      SB = __builtin_amdgcn_mfma_f32_32x32x16_bf16(kf, qb2, SB, 0, 0, 0);
    }

    bf16x8 pf0, pf1;
    softmax(SA, pf0, pf1, lA);
#pragma unroll
    for (int c = 0; c < 4; c++) {
      OA[c] = __builtin_amdgcn_mfma_f32_32x32x16_bf16(Vc[2 * c],     pf0, OA[c], 0, 0, 0);
      OA[c] = __builtin_amdgcn_mfma_f32_32x32x16_bf16(Vc[2 * c + 1], pf1, OA[c], 0, 0, 0);
    }
    softmax(SB, pf0, pf1, lB);
#pragma unroll
    for (int c = 0; c < 4; c++) {
      OB[c] = __builtin_amdgcn_mfma_f32_32x32x16_bf16(Vc[2 * c],     pf0, OB[c], 0, 0, 0);
      OB[c] = __builtin_amdgcn_mfma_f32_32x32x16_bf16(Vc[2 * c + 1], pf1, OB[c], 0, 0, 0);
    }

    if (lt < 63) {
      __builtin_amdgcn_sched_barrier(0);
      __builtin_amdgcn_s_barrier();          // raw: NO vmcnt(0) drain
      __builtin_amdgcn_sched_barrier(0);
    }
  }

  // ---- epilogue: l publish, kh-merge via ostage [ch][64], writeout ----
  float lfA = lA + __shfl_xor(lA, 32);
  float lfB = lB + __shfl_xor(lB, 32);
  if (lane < 32) { sm.redu[w][l32] = lfA; sm.redu[w][32 + l32] = lfB; }
  __syncthreads();                 // main-loop kbuf/qlds reads done
  const int hb = lane >> 5;
  if (kh == 0) {
#pragma unroll
    for (int c = 0; c < 4; c++) {
#pragma unroll
      for (int r = 0; r < 16; r++) {
        int ch = (chh * 4 + c) * 32 + (r & 3) + 8 * (r >> 2) + 4 * hb;
        sm.u.ostage[ch][l32]      = OA[c][r];
        sm.u.ostage[ch][32 + l32] = OB[c][r];
      }
    }
  }
  if (tid < 64) sm.rinv[tid] = 1.0f / (sm.redu[0][tid] + sm.redu[2][tid]);
  __syncthreads();
  if (kh == 1) {
#pragma unroll
    for (int c = 0; c < 4; c++) {
#pragma unroll
      for (int r = 0; r < 16; r++) {
        int ch = (chh * 4 + c) * 32 + (r & 3) + 8 * (r >> 2) + 4 * hb;
        sm.u.ostage[ch][l32]      += OA[c][r];
        sm.u.ostage[ch][32 + l32] += OB[c][r];
      }
    }
  }
  __syncthreads();

  const float gmm = gammap[0];
  const int pix = tid & 63;        // constant per thread across j
  const float ri = sm.rinv[pix];
#pragma unroll 1
  for (int j = 0; j < 64; ++j) {
    int ch = j * 4 + (tid >> 6);
    size_t g = ((size_t)(b * 256 + ch)) * 4096 + n0 + pix;
    out[g] = gmm * sm.u.ostage[ch][pix] * ri + x_main[g];
  }
}

// ---------------------------------------------------------------------------
extern "C" void kernel_launch(void* const* d_in, const int* in_sizes, int n_in,
                              void* d_out, int out_size, void* d_ws, size_t ws_size,
                              hipStream_t stream) {
  (void)in_sizes; (void)n_in; (void)out_size; (void)ws_size;
  const float* x  = (const float*)d_in[0];
  const float* z  = (const float*)d_in[1];
  const float* Wq = (const float*)d_in[2];
  const float* bq = (const float*)d_in[3];
  const float* Wk = (const float*)d_in[4];
  const float* bk = (const float*)d_in[5];
  const float* Wv = (const float*)d_in[6];
  const float* bv = (const float*)d_in[7];
  const float* gm = (const float*)d_in[8];
  float* out = (float*)d_out;

  char* ws = (char*)d_ws;
  const size_t MB = 1024 * 1024;
  __hip_bfloat16* qp  = (__hip_bfloat16*)(ws);             // 4 MiB
  __hip_bfloat16* kp  = (__hip_bfloat16*)(ws + 4 * MB);    // 4 MiB
  __hip_bfloat16* vp  = (__hip_bfloat16*)(ws + 8 * MB);    // 8 MiB
  __hip_bfloat16* wfp = (__hip_bfloat16*)(ws + 16 * MB);   // 256 KiB

  wprep_kernel<<<16, 256, 0, stream>>>(Wq, Wk, Wv, wfp);
  projfused   <<<512, 512, 0, stream>>>(x, z, wfp, bq, bk, bv, qp, kp, vp);
  attn_kernel <<<256, 256, 0, stream>>>(qp, kp, vp, x, gm, out);
}

// Round 11
// 224.517 us; speedup vs baseline: 1.0125x; 1.0125x over previous
//
#include <hip/hip_runtime.h>
#include <hip/hip_bf16.h>

// CrossAttentionFusion: B=4, C=Cs=256, CI=128, H=W=64 -> N=M=4096
// R17 = QBLK=64 (traffic/2) x split-K2 (concurrency restored) + merge:
//  - R16 post-mortem: halving traffic at 1 block/CU REGRESSED (108->137.5)
//    while R11 (3 blocks/CU, full traffic) matched R13 => attn is L2-service
//    bound at a concurrency-dependent effective BW (~1.8TB/s/XCD at 64
//    blocks/XCD). Need BOTH low bytes and high block concurrency.
//  - attn_split<1>: grid 512 = (b, qt2, kt2). Each block: 64 q (dual-Q R16
//    body, V regs reused A+B) x 32 K-tiles, kbuf[3] counted-vmcnt pipeline.
//    2 blocks/CU. Writes unnormalized O-partials + l-partials (fixed exp2
//    anchor => partials add exactly). merge normalizes + gamma + residual.
//  - attn_split<0>: exact R16 single-pass (fallback if workspace small).
//  - projfused: wprep folded in — waves build W-frags from global W with the
//    identical transform (one less kernel launch; wfr round-trip gone).
//
// qk-frag (Q B-op / K A-op), per 32-row group g:
//   addr = g*4096 + (ch>>4)*512 + ((ch>>3)&1)*256 + row*8 + (ch&7)
//   (K rows permuted: row = l32^12 if (l32>>2)&3 in {1,2} -> shuffle-free PV)
// V-frag (PV A-op), per 32-key group g: addr = g*8192 + (ch>>5)*1024
//   + ((key>>4)&1)*512 + ((key>>3)&1)*256 + (ch&31)*8 + (key&7)

typedef __bf16  bf16x8  __attribute__((ext_vector_type(8)));
typedef float   f32x16  __attribute__((ext_vector_type(16)));

#define LOG2E 1.4426950408889634f

union BF8 { __hip_bfloat162 h[4]; bf16x8 v; };
union U4  { unsigned u[4]; bf16x8 v; };

__device__ inline bf16x8 pack8(const float f[8]) {
  BF8 u;
#pragma unroll
  for (int i = 0; i < 4; i++)
    u.h[i] = __float22bfloat162_rn(float2{f[2 * i], f[2 * i + 1]});
  return u.v;
}

__device__ inline void dma16(const void* g, void* l) {
  __builtin_amdgcn_global_load_lds(
      (const __attribute__((address_space(1))) unsigned int*)g,
      (__attribute__((address_space(3))) unsigned int*)l, 16, 0, 0);
}

// ---------------------------------------------------------------------------
// projfused: stage input tile via LDS, pack to frag-LDS, MFMA from LDS,
// direct scatter stores. W-frags built inline from global W (wprep folded).
// Grid 512: [0,256) q(x), [256,512) kv(z). 512 threads, 2 blocks/CU.
// ---------------------------------------------------------------------------
struct PFSmem {
  float stg[128 * 68];
  alignas(16) __hip_bfloat16 frag[16384];
};

__device__ inline void wload(const float* Ws, int ot, int l32, int half,
                             bf16x8* wfg) {
  const float* wsrc = Ws + (ot * 32 + l32) * 256 + half * 8;
#pragma unroll
  for (int cs = 0; cs < 16; cs++) {
    float f[8];
#pragma unroll
    for (int j = 0; j < 8; j++) f[j] = wsrc[cs * 16 + j];
    wfg[cs] = pack8(f);
  }
}

__global__ __launch_bounds__(512, 2) void projfused(
    const float* __restrict__ x, const float* __restrict__ z,
    const float* __restrict__ Wq, const float* __restrict__ Wk,
    const float* __restrict__ Wv,
    const float* __restrict__ bq, const float* __restrict__ bk,
    const float* __restrict__ bv,
    __hip_bfloat16* __restrict__ qp, __hip_bfloat16* __restrict__ kp,
    __hip_bfloat16* __restrict__ vp)
{
  __shared__ PFSmem sm;
  const int bi = blockIdx.x;
  const bool qmode = bi < 256;
  const int j2 = qmode ? bi : bi - 256;
  const int b = j2 >> 6, pc = j2 & 63;
  const float* in = qmode ? x : z;
  const size_t ib = (size_t)b * 256 * 4096 + pc * 64;

  const int tid = threadIdx.x, w = tid >> 6, lane = tid & 63,
            l32 = lane & 31, half = lane >> 5;
  const int pix4 = (tid & 15) * 4;

  // ---- stage/pack half 0 (ch 0..127 -> cs 0..7) ----
#pragma unroll
  for (int it = 0; it < 4; it++) {
    int ch = it * 32 + (tid >> 4);
    float4 v4 = *(const float4*)&in[ib + (size_t)ch * 4096 + pix4];
    *(float4*)&sm.stg[ch * 68 + pix4] = v4;
  }
  __syncthreads();
#pragma unroll
  for (int i = 0; i < 2; i++) {
    int c = i * 512 + tid;
    int grp = c >> 9, csl = (c >> 6) & 7, rem = c & 63;
    int hf = rem >> 5, lr = rem & 31;
    int chb = csl * 16 + hf * 8;
    float f[8];
#pragma unroll
    for (int j = 0; j < 8; j++) f[j] = sm.stg[(chb + j) * 68 + grp * 32 + lr];
    *(bf16x8*)(sm.frag + grp * 8192 + csl * 512 + hf * 256 + lr * 8) = pack8(f);
  }
  __syncthreads();

  // ---- stage/pack half 1 (ch 128..255 -> cs 8..15) ----
#pragma unroll
  for (int it = 0; it < 4; it++) {
    int ch = it * 32 + (tid >> 4);
    float4 v4 = *(const float4*)&in[ib + (size_t)(128 + ch) * 4096 + pix4];
    *(float4*)&sm.stg[ch * 68 + pix4] = v4;
  }
  __syncthreads();
#pragma unroll
  for (int i = 0; i < 2; i++) {
    int c = i * 512 + tid;
    int grp = c >> 9, csl = (c >> 6) & 7, rem = c & 63;
    int hf = rem >> 5, lr = rem & 31;
    int chb = csl * 16 + hf * 8;
    float f[8];
#pragma unroll
    for (int j = 0; j < 8; j++) f[j] = sm.stg[(chb + j) * 68 + grp * 32 + lr];
    *(bf16x8*)(sm.frag + grp * 8192 + (csl + 8) * 512 + hf * 256 + lr * 8) =
        pack8(f);
  }
  __syncthreads();

  const int t4 = (l32 >> 2) & 3;
  const int kperm = (t4 == 1 || t4 == 2) ? (l32 ^ 12) : l32;

  if (qmode) {
    const int ot = w >> 1, pg = w & 1;
    bf16x8 bfr[16];
#pragma unroll
    for (int cs = 0; cs < 16; cs++)
      bfr[cs] = *(const bf16x8*)(sm.frag + pg * 8192 + cs * 512 + lane * 8);
    bf16x8 wfg[16];
    wload(Wq, ot, l32, half, wfg);
    float bb[16];
#pragma unroll
    for (int r = 0; r < 16; r++)
      bb[r] = bq[ot * 32 + (r & 3) + 8 * (r >> 2) + 4 * half];
    f32x16 O = {};
#pragma unroll
    for (int cs = 0; cs < 16; cs++)
      O = __builtin_amdgcn_mfma_f32_32x32x16_bf16(wfg[cs], bfr[cs], O, 0, 0, 0);
    __hip_bfloat16* qb = qp + ((size_t)(b * 128 + pc * 2 + pg)) * 4096;
#pragma unroll
    for (int r = 0; r < 16; r++) {
      int oc = ot * 32 + (r & 3) + 8 * (r >> 2) + 4 * half;
      qb[(oc >> 4) * 512 + ((oc >> 3) & 1) * 256 + l32 * 8 + (oc & 7)] =
          __float2bfloat16((O[r] + bb[r]) * LOG2E);
    }
  } else {
    const int pg = w & 1;
    bf16x8 bfr[16];
#pragma unroll
    for (int cs = 0; cs < 16; cs++)
      bfr[cs] = *(const bf16x8*)(sm.frag + pg * 8192 + cs * 512 + lane * 8);
    const size_t pgg = (size_t)(b * 128 + pc * 2 + pg);
#pragma unroll
    for (int jj = 0; jj < 3; jj++) {
      const int t = (w + jj * 8) >> 1;         // [0,12): t<4 K, else V tile t-4
      const bool isK = (t < 4);
      const int tt = isK ? t : t - 4;
      bf16x8 wfg[16];
      wload(isK ? Wk : Wv, tt, l32, half, wfg);
      const float* bias = isK ? bk : bv;
      float bb[16];
#pragma unroll
      for (int r = 0; r < 16; r++)
        bb[r] = bias[tt * 32 + (r & 3) + 8 * (r >> 2) + 4 * half];
      f32x16 O = {};
#pragma unroll
      for (int cs = 0; cs < 16; cs++)
        O = __builtin_amdgcn_mfma_f32_32x32x16_bf16(wfg[cs], bfr[cs], O, 0, 0, 0);
      if (isK) {
        __hip_bfloat16* kb = kp + pgg * 4096;
#pragma unroll
        for (int r = 0; r < 16; r++) {
          int oc = t * 32 + (r & 3) + 8 * (r >> 2) + 4 * half;
          kb[(oc >> 4) * 512 + ((oc >> 3) & 1) * 256 + kperm * 8 + (oc & 7)] =
              __float2bfloat16(O[r] + bb[r]);
        }
      } else {
        __hip_bfloat16* vb = vp + pgg * 8192 + tt * 1024
            + (l32 >> 4) * 512 + ((l32 >> 3) & 1) * 256 + (l32 & 7);
#pragma unroll
        for (int r = 0; r < 16; r++) {
          int rr = (r & 3) + 8 * (r >> 2) + 4 * half;
          vb[rr * 8] = __float2bfloat16(O[r] + bb[r]);
        }
      }
    }
  }
}

// ---------------------------------------------------------------------------
// attn R17: QBLK=64 dual-Q body (R16), templated on SPLIT.
// SPLIT=1: grid 512 = (b, qt2, kt2), 32 tiles -> partials to workspace.
// SPLIT=0: grid 256 (exact R16 single-pass fallback).
// 4 waves = (kh, chh); kbuf[3] counted-vmcnt K-DMA; raw s_barrier main loop.
// ---------------------------------------------------------------------------
struct AttnSmem {
  union {
    struct {
      __hip_bfloat16 kbuf[3][8192];   // 48 KiB triple buffer
      __hip_bfloat16 qlds[8192];      // 16 KiB: q-tiles A (0..4095), B (+4096)
    } m;
    float ostage[256][65];            // 66.6 KiB epilogue [ch][q64], pad 65
  } u;
  float redu[4][64];
  float rinv[64];
};

template <int SPLIT>
__global__ __launch_bounds__(256, 2) void attn_kernel(
    const __hip_bfloat16* __restrict__ qv, const __hip_bfloat16* __restrict__ kv,
    const __hip_bfloat16* __restrict__ vv,
    const float* __restrict__ x_main, const float* __restrict__ gammap,
    float* __restrict__ out,
    float* __restrict__ part, float* __restrict__ lpart)
{
  __shared__ AttnSmem sm;
  const int i   = blockIdx.x;          // 512 (SPLIT) or 256
  const int b   = (i & 7) >> 1;        // XCD-pair -> batch (K+V L2-resident)
  int qt2, kt2;
  if (SPLIT) { int j = i >> 3; kt2 = j >> 5; qt2 = ((j & 31) << 1) | (i & 1); }
  else       { kt2 = 0;        qt2 = ((i >> 3) << 1) | (i & 1); }
  const int NT = SPLIT ? 32 : 64;      // K-tiles of 128 keys
  const int sbase = SPLIT ? kt2 * 32 : 0;
  const int qtA = qt2 * 2;
  const int n0  = qt2 * 64;
  const int tid = threadIdx.x;
  const int w   = tid >> 6, lane = tid & 63, l32 = lane & 31;
  const int kh  = w >> 1, chh = w & 1;
  const int t0  = qt2 & (NT - 1);      // stagger: de-correlate block streams

  // Q (both tiles) -> LDS: 8192 bf16, contiguous in qp layout
  {
    const __hip_bfloat16* qsrc = qv + ((size_t)(b * 128 + qtA)) * 4096;
#pragma unroll
    for (int j = 0; j < 4; j++)
      *(bf16x8*)(sm.u.m.qlds + j * 2048 + tid * 8) =
          *(const bf16x8*)(qsrc + j * 2048 + tid * 8);
  }

  const __hip_bfloat16* kg = kv + (size_t)(b * 128) * 4096;
  const __hip_bfloat16* vg = vv + (size_t)(b * 128) * 8192;

  auto stage = [&](int tl, int par) {   // tl = local tile idx in [0,NT)
    __hip_bfloat16* kd = sm.u.m.kbuf[par];
    const __hip_bfloat16* ksrc = kg + (size_t)(sbase + tl) * 8192 + lane * 8;
#pragma unroll
    for (int c = 0; c < 4; c++) {
      int ck = w * 4 + c;
      dma16(ksrc + ck * 512, kd + ck * 512 + lane * 8);
    }
  };

  f32x16 OA[4], OB[4];
#pragma unroll
  for (int c = 0; c < 4; c++)
#pragma unroll
    for (int r = 0; r < 16; r++) { OA[c][r] = 0.f; OB[c][r] = 0.f; }

  float lA = 0.f, lB = 0.f;

  auto softmax = [&](const f32x16& S, bf16x8& pf0, bf16x8& pf1, float& lacc) {
    unsigned p2[8];
    float lsub = 0.f;
#pragma unroll
    for (int i2 = 0; i2 < 8; i2++) {
      float a = exp2f(S[2 * i2]     - 64.0f);
      float c = exp2f(S[2 * i2 + 1] - 64.0f);
      lsub += a + c;
      union { __hip_bfloat162 h; unsigned u; } cv;
      cv.h = __float22bfloat162_rn(float2{a, c});
      p2[i2] = cv.u;
    }
    lacc += lsub;
    U4 f0, f1;
    f0.u[0] = p2[0]; f0.u[1] = p2[1]; f0.u[2] = p2[2]; f0.u[3] = p2[3];
    f1.u[0] = p2[4]; f1.u[1] = p2[5]; f1.u[2] = p2[6]; f1.u[3] = p2[7];
    pf0 = f0.v; pf1 = f1.v;
  };

  // ---- prologue: stage first two tiles; one-time full drain ----
  stage(t0, 0);
  stage((t0 + 1) & (NT - 1), 1);
  __syncthreads();

  // ---- main loop: 1 raw barrier/tile, vmcnt never drained to 0 ----
#pragma unroll 1
  for (int lt = 0; lt < NT; ++lt) {
    const int ta = sbase + ((lt + t0) & (NT - 1));

    // V frags FIRST (older than this iter's DMA in the vmcnt FIFO)
    const __hip_bfloat16* vb = vg + (size_t)(ta * 2 + kh) * 8192
                             + chh * 4096 + lane * 8;
    bf16x8 Vc[8];
#pragma unroll
    for (int c = 0; c < 4; c++) {
      Vc[2 * c]     = *(const bf16x8*)(vb + c * 1024);
      Vc[2 * c + 1] = *(const bf16x8*)(vb + c * 1024 + 512);
    }
    __builtin_amdgcn_sched_barrier(0);   // pin V-issue before DMA-issue

    if (lt < NT - 2) stage((lt + 2 + t0) & (NT - 1), (lt + 2) % 3);

    // QK_A and QK_B: shared kf load, two independent MFMA chains
    const __hip_bfloat16* kbase = sm.u.m.kbuf[lt % 3] + kh * 4096 + lane * 8;
    const __hip_bfloat16* qab   = sm.u.m.qlds + lane * 8;
    f32x16 SA = {}, SB = {};
#pragma unroll
    for (int cs = 0; cs < 8; cs++) {
      bf16x8 kf  = *(const bf16x8*)(kbase + cs * 512);
      bf16x8 qa  = *(const bf16x8*)(qab + cs * 512);
      bf16x8 qb2 = *(const bf16x8*)(qab + 4096 + cs * 512);
      SA = __builtin_amdgcn_mfma_f32_32x32x16_bf16(kf, qa,  SA, 0, 0, 0);
      SB = __builtin_amdgcn_mfma_f32_32x32x16_bf16(kf, qb2, SB, 0, 0, 0);
    }

    bf16x8 pf0, pf1;
    softmax(SA, pf0, pf1, lA);
#pragma unroll
    for (int c = 0; c < 4; c++) {
      OA[c] = __builtin_amdgcn_mfma_f32_32x32x16_bf16(Vc[2 * c],     pf0, OA[c], 0, 0, 0);
      OA[c] = __builtin_amdgcn_mfma_f32_32x32x16_bf16(Vc[2 * c + 1], pf1, OA[c], 0, 0, 0);
    }
    softmax(SB, pf0, pf1, lB);
#pragma unroll
    for (int c = 0; c < 4; c++) {
      OB[c] = __builtin_amdgcn_mfma_f32_32x32x16_bf16(Vc[2 * c],     pf0, OB[c], 0, 0, 0);
      OB[c] = __builtin_amdgcn_mfma_f32_32x32x16_bf16(Vc[2 * c + 1], pf1, OB[c], 0, 0, 0);
    }

    if (lt < NT - 1) {
      __builtin_amdgcn_sched_barrier(0);
      __builtin_amdgcn_s_barrier();          // raw: NO vmcnt(0) drain
      __builtin_amdgcn_sched_barrier(0);
    }
  }

  // ---- epilogue ----
  float lfA = lA + __shfl_xor(lA, 32);
  float lfB = lB + __shfl_xor(lB, 32);
  if (lane < 32) { sm.redu[w][l32] = lfA; sm.redu[w][32 + l32] = lfB; }
  __syncthreads();                 // main-loop kbuf/qlds reads done
  const int hb = lane >> 5;
  if (kh == 0) {
#pragma unroll
    for (int c = 0; c < 4; c++) {
#pragma unroll
      for (int r = 0; r < 16; r++) {
        int ch = (chh * 4 + c) * 32 + (r & 3) + 8 * (r >> 2) + 4 * hb;
        sm.u.ostage[ch][l32]      = OA[c][r];
        sm.u.ostage[ch][32 + l32] = OB[c][r];
      }
    }
  }
  if (!SPLIT) {
    if (tid < 64) sm.rinv[tid] = 1.0f / (sm.redu[0][tid] + sm.redu[2][tid]);
  }
  __syncthreads();
  if (kh == 1) {
#pragma unroll
    for (int c = 0; c < 4; c++) {
#pragma unroll
      for (int r = 0; r < 16; r++) {
        int ch = (chh * 4 + c) * 32 + (r & 3) + 8 * (r >> 2) + 4 * hb;
        sm.u.ostage[ch][l32]      += OA[c][r];
        sm.u.ostage[ch][32 + l32] += OB[c][r];
      }
    }
  }
  __syncthreads();

  if (SPLIT) {
    const int pblk = (b * 64 + qt2) * 2 + kt2;
    if (tid < 64)
      lpart[(size_t)pblk * 64 + tid] = sm.redu[0][tid] + sm.redu[2][tid];
    float* pb = part + (size_t)pblk * 16384;
#pragma unroll 4
    for (int j = 0; j < 64; ++j) {
      int idx = j * 256 + tid;
      pb[idx] = sm.u.ostage[idx >> 6][idx & 63];
    }
  } else {
    const float gmm = gammap[0];
    const int pix = tid & 63;
    const float ri = sm.rinv[pix];
#pragma unroll 1
    for (int j = 0; j < 64; ++j) {
      int ch = j * 4 + (tid >> 6);
      size_t g = ((size_t)(b * 256 + ch)) * 4096 + n0 + pix;
      out[g] = gmm * sm.u.ostage[ch][pix] * ri + x_main[g];
    }
  }
}

// ---------------------------------------------------------------------------
// merge: (O0 + O1) / (l0 + l1) * gamma + x_main. Grid 256 = (b, qt2).
// BW-bound: 32MB partials + 16.7MB x + 16.7MB out.
// ---------------------------------------------------------------------------
__global__ __launch_bounds__(256) void merge_kernel(
    const float* __restrict__ part, const float* __restrict__ lpart,
    const float* __restrict__ x_main, const float* __restrict__ gammap,
    float* __restrict__ out)
{
  const int i = blockIdx.x;            // 256
  const int b = i >> 6, qt2 = i & 63, n0 = qt2 * 64;
  const int tid = threadIdx.x, pix = tid & 63;
  const size_t pb = (size_t)((b * 64 + qt2) * 2) * 16384;
  const float* lp = lpart + (size_t)((b * 64 + qt2) * 2) * 64;
  const float rv = gammap[0] / (lp[pix] + lp[64 + pix]);
#pragma unroll 4
  for (int j = 0; j < 64; ++j) {
    int idx = j * 256 + tid;           // ch = idx>>6, q = idx&63 (= pix)
    int ch = idx >> 6;
    size_t g = ((size_t)(b * 256 + ch)) * 4096 + n0 + pix;
    float o = (part[pb + idx] + part[pb + 16384 + idx]) * rv;
    out[g] = o + x_main[g];
  }
}

// ---------------------------------------------------------------------------
extern "C" void kernel_launch(void* const* d_in, const int* in_sizes, int n_in,
                              void* d_out, int out_size, void* d_ws, size_t ws_size,
                              hipStream_t stream) {
  (void)in_sizes; (void)n_in; (void)out_size;
  const float* x  = (const float*)d_in[0];
  const float* z  = (const float*)d_in[1];
  const float* Wq = (const float*)d_in[2];
  const float* bq = (const float*)d_in[3];
  const float* Wk = (const float*)d_in[4];
  const float* bk = (const float*)d_in[5];
  const float* Wv = (const float*)d_in[6];
  const float* bv = (const float*)d_in[7];
  const float* gm = (const float*)d_in[8];
  float* out = (float*)d_out;

  char* ws = (char*)d_ws;
  const size_t MB = 1024 * 1024;
  __hip_bfloat16* qp  = (__hip_bfloat16*)(ws);             // 4 MiB
  __hip_bfloat16* kp  = (__hip_bfloat16*)(ws + 4 * MB);    // 4 MiB
  __hip_bfloat16* vp  = (__hip_bfloat16*)(ws + 8 * MB);    // 8 MiB
  float* part  = (float*)(ws + 16 * MB);                   // 32 MiB (split)
  float* lpart = (float*)(ws + 48 * MB);                   // 256 KiB (split)

  const bool split = ws_size >= 49 * MB;   // R11 demonstrated >=66MB exists

  projfused<<<512, 512, 0, stream>>>(x, z, Wq, Wk, Wv, bq, bk, bv, qp, kp, vp);
  if (split) {
    attn_kernel<1><<<512, 256, 0, stream>>>(qp, kp, vp, x, gm, out, part, lpart);
    merge_kernel<<<256, 256, 0, stream>>>(part, lpart, x, gm, out);
  } else {
    attn_kernel<0><<<256, 256, 0, stream>>>(qp, kp, vp, x, gm, out, part, lpart);
  }
}

// Round 12
// 216.801 us; speedup vs baseline: 1.0486x; 1.0356x over previous
//
#include <hip/hip_runtime.h>
#include <hip/hip_bf16.h>

// CrossAttentionFusion: B=4, C=Cs=256, CI=128, H=W=64 -> N=M=4096
// R18 = R15 base (best total 202.6) + projfused store/chain fixes:
//  - R17 post-mortem: traffic/2 at full concurrency moved attn only -2.5%
//    => attn ~104-108 is structural for this decomposition. Split-K merge
//    is net-negative. Inline wload cost ~11us -> wprep/wfr restored.
//  - projfused: (a) q/k outputs staged in LDS (stg free after pack) in the
//    exact global layout, then CONTIGUOUS bf16x8 copy-out — replaces 16
//    2-B scatter stores/thread whose 64 lanes hit 64 distinct 16-B chunks;
//    (b) every 16-deep MFMA job split into two independent 8-deep chains.
//  - attn: R13 body (measured 106.5/108) + QK dual-chain (Sa/Sb summed in
//    softmax) — only change.
//
// qk-frag (Q B-op / K A-op), per 32-row group g:
//   addr = g*4096 + (ch>>4)*512 + ((ch>>3)&1)*256 + row*8 + (ch&7)
//   (K rows permuted: row = l32^12 if (l32>>2)&3 in {1,2} -> shuffle-free PV)
// V-frag (PV A-op), per 32-key group g: addr = g*8192 + (ch>>5)*1024
//   + ((key>>4)&1)*512 + ((key>>3)&1)*256 + (ch&31)*8 + (key&7)

typedef __bf16  bf16x8  __attribute__((ext_vector_type(8)));
typedef float   f32x16  __attribute__((ext_vector_type(16)));

#define LOG2E 1.4426950408889634f

union BF8 { __hip_bfloat162 h[4]; bf16x8 v; };
union U4  { unsigned u[4]; bf16x8 v; };

__device__ inline bf16x8 pack8(const float f[8]) {
  BF8 u;
#pragma unroll
  for (int i = 0; i < 4; i++)
    u.h[i] = __float22bfloat162_rn(float2{f[2 * i], f[2 * i + 1]});
  return u.v;
}

__device__ inline void dma16(const void* g, void* l) {
  __builtin_amdgcn_global_load_lds(
      (const __attribute__((address_space(1))) unsigned int*)g,
      (__attribute__((address_space(3))) unsigned int*)l, 16, 0, 0);
}

// ---------------------------------------------------------------------------
// wprep: W -> W-frag bf16 (16 blocks).  (R15 verbatim)
// ---------------------------------------------------------------------------
__global__ __launch_bounds__(256) void wprep_kernel(
    const float* __restrict__ Wq, const float* __restrict__ Wk,
    const float* __restrict__ Wv, __hip_bfloat16* __restrict__ wfr)
{
  const int base = blockIdx.x * 1024;
  const int tid = threadIdx.x;
#pragma unroll
  for (int i = 0; i < 4; i++) {
    int c = base + i * 256 + tid;          // [0, 16384)
    const float* Ws; __hip_bfloat16* dst; int rc;
    if (c < 4096)      { Ws = Wq; dst = wfr;          rc = c; }
    else if (c < 8192) { Ws = Wk; dst = wfr + 32768;  rc = c - 4096; }
    else               { Ws = Wv; dst = wfr + 65536;  rc = c - 8192; }
    int ot = rc >> 10, cs = (rc >> 6) & 15, rem = rc & 63;
    int hf = rem >> 5, l32 = rem & 31;
    const float* src = Ws + (ot * 32 + l32) * 256 + cs * 16 + hf * 8;
    float f[8];
#pragma unroll
    for (int j = 0; j < 8; j++) f[j] = src[j];
    *(bf16x8*)(dst + ot * 8192 + cs * 512 + hf * 256 + l32 * 8) = pack8(f);
  }
}

// ---------------------------------------------------------------------------
// projfused: stage input via LDS, pack to frag-LDS, dual-chain MFMA from LDS.
// q/k outputs staged in LDS (stg reuse) -> contiguous bf16x8 stores; v direct.
// Grid 512: [0,256) q(x), [256,512) kv(z). 512 threads, 2 blocks/CU.
// ---------------------------------------------------------------------------
struct PFSmem {
  float stg[128 * 68];                     // 34,816 B; reused as bf16 out-stage
  alignas(16) __hip_bfloat16 frag[16384];  // 32,768 B frag layout
};

__global__ __launch_bounds__(512, 2) void projfused(
    const float* __restrict__ x, const float* __restrict__ z,
    const __hip_bfloat16* __restrict__ wfr,
    const float* __restrict__ bq, const float* __restrict__ bk,
    const float* __restrict__ bv,
    __hip_bfloat16* __restrict__ qp, __hip_bfloat16* __restrict__ kp,
    __hip_bfloat16* __restrict__ vp)
{
  __shared__ PFSmem sm;
  const int bi = blockIdx.x;
  const bool qmode = bi < 256;
  const int j2 = qmode ? bi : bi - 256;
  const int b = j2 >> 6, pc = j2 & 63;
  const float* in = qmode ? x : z;
  const size_t ib = (size_t)b * 256 * 4096 + pc * 64;

  const int tid = threadIdx.x, w = tid >> 6, lane = tid & 63,
            l32 = lane & 31, half = lane >> 5;
  const int pix4 = (tid & 15) * 4;

  // ---- stage/pack half 0 (ch 0..127 -> cs 0..7) ----
#pragma unroll
  for (int it = 0; it < 4; it++) {
    int ch = it * 32 + (tid >> 4);
    float4 v4 = *(const float4*)&in[ib + (size_t)ch * 4096 + pix4];
    *(float4*)&sm.stg[ch * 68 + pix4] = v4;
  }
  __syncthreads();
#pragma unroll
  for (int i = 0; i < 2; i++) {
    int c = i * 512 + tid;
    int grp = c >> 9, csl = (c >> 6) & 7, rem = c & 63;
    int hf = rem >> 5, lr = rem & 31;
    int chb = csl * 16 + hf * 8;
    float f[8];
#pragma unroll
    for (int j = 0; j < 8; j++) f[j] = sm.stg[(chb + j) * 68 + grp * 32 + lr];
    *(bf16x8*)(sm.frag + grp * 8192 + csl * 512 + hf * 256 + lr * 8) = pack8(f);
  }
  __syncthreads();

  // ---- stage/pack half 1 (ch 128..255 -> cs 8..15) ----
#pragma unroll
  for (int it = 0; it < 4; it++) {
    int ch = it * 32 + (tid >> 4);
    float4 v4 = *(const float4*)&in[ib + (size_t)(128 + ch) * 4096 + pix4];
    *(float4*)&sm.stg[ch * 68 + pix4] = v4;
  }
  __syncthreads();
#pragma unroll
  for (int i = 0; i < 2; i++) {
    int c = i * 512 + tid;
    int grp = c >> 9, csl = (c >> 6) & 7, rem = c & 63;
    int hf = rem >> 5, lr = rem & 31;
    int chb = csl * 16 + hf * 8;
    float f[8];
#pragma unroll
    for (int j = 0; j < 8; j++) f[j] = sm.stg[(chb + j) * 68 + grp * 32 + lr];
    *(bf16x8*)(sm.frag + grp * 8192 + (csl + 8) * 512 + hf * 256 + lr * 8) =
        pack8(f);
  }
  __syncthreads();                       // frag complete; stg now free

  const int t4 = (l32 >> 2) & 3;
  const int kperm = (t4 == 1 || t4 == 2) ? (l32 ^ 12) : l32;
  __hip_bfloat16* ostg = (__hip_bfloat16*)sm.stg;   // 16 KiB out-stage

  if (qmode) {
    const int ot = w >> 1, pg = w & 1;
    bf16x8 bfr[16];
#pragma unroll
    for (int cs = 0; cs < 16; cs++)
      bfr[cs] = *(const bf16x8*)(sm.frag + pg * 8192 + cs * 512 + lane * 8);
    const __hip_bfloat16* wp = wfr + ot * 8192 + lane * 8;
    bf16x8 wfg[16];
#pragma unroll
    for (int cs = 0; cs < 16; cs++) wfg[cs] = *(const bf16x8*)(wp + cs * 512);
    float bb[16];
#pragma unroll
    for (int r = 0; r < 16; r++)
      bb[r] = bq[ot * 32 + (r & 3) + 8 * (r >> 2) + 4 * half];
    f32x16 Oa = {}, Ob = {};
#pragma unroll
    for (int cs = 0; cs < 8; cs++) {     // two independent 8-deep chains
      Oa = __builtin_amdgcn_mfma_f32_32x32x16_bf16(wfg[cs],     bfr[cs],     Oa, 0, 0, 0);
      Ob = __builtin_amdgcn_mfma_f32_32x32x16_bf16(wfg[cs + 8], bfr[cs + 8], Ob, 0, 0, 0);
    }
    // stage in exact qp layout, then contiguous copy-out
#pragma unroll
    for (int r = 0; r < 16; r++) {
      int oc = ot * 32 + (r & 3) + 8 * (r >> 2) + 4 * half;
      ostg[pg * 4096 + (oc >> 4) * 512 + ((oc >> 3) & 1) * 256 + l32 * 8 +
           (oc & 7)] =
          __float2bfloat16((Oa[r] + Ob[r] + bb[r]) * LOG2E);
    }
    __syncthreads();
    __hip_bfloat16* qb = qp + ((size_t)(b * 128 + pc * 2)) * 4096;
    *(bf16x8*)(qb + tid * 8)        = *(const bf16x8*)(ostg + tid * 8);
    *(bf16x8*)(qb + 4096 + tid * 8) = *(const bf16x8*)(ostg + 4096 + tid * 8);
  } else {
    const int pg = w & 1;
    bf16x8 bfr[16];
#pragma unroll
    for (int cs = 0; cs < 16; cs++)
      bfr[cs] = *(const bf16x8*)(sm.frag + pg * 8192 + cs * 512 + lane * 8);
    const size_t pgg = (size_t)(b * 128 + pc * 2 + pg);

    // ---- job 0: K tile t = w>>1 (all waves do K first) ----
    {
      const int t = w >> 1;
      const __hip_bfloat16* wp = wfr + 32768 + t * 8192 + lane * 8;
      bf16x8 wfg[16];
#pragma unroll
      for (int cs = 0; cs < 16; cs++) wfg[cs] = *(const bf16x8*)(wp + cs * 512);
      float bb[16];
#pragma unroll
      for (int r = 0; r < 16; r++)
        bb[r] = bk[t * 32 + (r & 3) + 8 * (r >> 2) + 4 * half];
      f32x16 Oa = {}, Ob = {};
#pragma unroll
      for (int cs = 0; cs < 8; cs++) {
        Oa = __builtin_amdgcn_mfma_f32_32x32x16_bf16(wfg[cs],     bfr[cs],     Oa, 0, 0, 0);
        Ob = __builtin_amdgcn_mfma_f32_32x32x16_bf16(wfg[cs + 8], bfr[cs + 8], Ob, 0, 0, 0);
      }
#pragma unroll
      for (int r = 0; r < 16; r++) {
        int oc = t * 32 + (r & 3) + 8 * (r >> 2) + 4 * half;
        ostg[pg * 4096 + (oc >> 4) * 512 + ((oc >> 3) & 1) * 256 + kperm * 8 +
             (oc & 7)] = __float2bfloat16(Oa[r] + Ob[r] + bb[r]);
      }
    }
    __syncthreads();
    {
      __hip_bfloat16* kb = kp + ((size_t)(b * 128 + pc * 2)) * 4096;
      *(bf16x8*)(kb + tid * 8)        = *(const bf16x8*)(ostg + tid * 8);
      *(bf16x8*)(kb + 4096 + tid * 8) = *(const bf16x8*)(ostg + 4096 + tid * 8);
    }

    // ---- jobs 1,2: V tiles (direct stores — already 16-B-chunk granular) ----
#pragma unroll
    for (int jj = 1; jj < 3; jj++) {
      const int t = (w + jj * 8) >> 1;         // [4,12): V tile t-4
      const int tt = t - 4;
      const __hip_bfloat16* wp = wfr + 65536 + tt * 8192 + lane * 8;
      bf16x8 wfg[16];
#pragma unroll
      for (int cs = 0; cs < 16; cs++) wfg[cs] = *(const bf16x8*)(wp + cs * 512);
      float bb[16];
#pragma unroll
      for (int r = 0; r < 16; r++)
        bb[r] = bv[tt * 32 + (r & 3) + 8 * (r >> 2) + 4 * half];
      f32x16 Oa = {}, Ob = {};
#pragma unroll
      for (int cs = 0; cs < 8; cs++) {
        Oa = __builtin_amdgcn_mfma_f32_32x32x16_bf16(wfg[cs],     bfr[cs],     Oa, 0, 0, 0);
        Ob = __builtin_amdgcn_mfma_f32_32x32x16_bf16(wfg[cs + 8], bfr[cs + 8], Ob, 0, 0, 0);
      }
      __hip_bfloat16* vb = vp + pgg * 8192 + tt * 1024
          + (l32 >> 4) * 512 + ((l32 >> 3) & 1) * 256 + (l32 & 7);
#pragma unroll
      for (int r = 0; r < 16; r++) {
        int rr = (r & 3) + 8 * (r >> 2) + 4 * half;
        vb[rr * 8] = __float2bfloat16(Oa[r] + Ob[r] + bb[r]);
      }
    }
  }
}

// ---------------------------------------------------------------------------
// attn: R13 body (measured 106.5/108) + QK dual-chain. Grid 512, 4 waves.
// kbuf[3] counted-vmcnt K-DMA; raw s_barrier main loop; single-pass output.
// ---------------------------------------------------------------------------
struct AttnSmem {
  union {
    __hip_bfloat16 kbuf[3][8192];   // 3 x 16 KiB triple buffer
    float ostage[256][33];          // epilogue [ch][q], pad 33
  } u;
  float redu[4][32];
  float rinv[32];
};

__global__ __launch_bounds__(256, 3) void attn_kernel(
    const __hip_bfloat16* __restrict__ qv, const __hip_bfloat16* __restrict__ kv,
    const __hip_bfloat16* __restrict__ vv,
    const float* __restrict__ x_main, const float* __restrict__ gammap,
    float* __restrict__ out)
{
  __shared__ AttnSmem sm;
  const int i  = blockIdx.x;           // 512 blocks
  const int b  = (i & 7) >> 1;         // XCD-pair -> batch (K+V L2-resident)
  const int qt = ((i >> 3) << 1) | (i & 1);
  const int n0 = qt * 32;
  const int tid  = threadIdx.x;
  const int w    = tid >> 6, lane = tid & 63, l32 = lane & 31;
  const int kh   = w >> 1, chh = w & 1;
  const int t0   = qt & 63;            // stagger: de-correlate block streams

  bf16x8 qf[8];
  {
    const __hip_bfloat16* qb = qv + ((size_t)(b * 128 + qt)) * 4096 + lane * 8;
#pragma unroll
    for (int cs = 0; cs < 8; cs++) qf[cs] = *(const bf16x8*)(qb + cs * 512);
  }

  const __hip_bfloat16* kg = kv + (size_t)(b * 128) * 4096;
  const __hip_bfloat16* vg = vv + (size_t)(b * 128) * 8192;

  auto stage = [&](int ta, int par) {
    __hip_bfloat16* kd = sm.u.kbuf[par];
    const __hip_bfloat16* ksrc = kg + (size_t)ta * 8192 + lane * 8;
#pragma unroll
    for (int c = 0; c < 4; c++) {
      int ck = w * 4 + c;
      dma16(ksrc + ck * 512, kd + ck * 512 + lane * 8);
    }
  };

  f32x16 Oacc[4];
#pragma unroll
  for (int c = 0; c < 4; c++)
#pragma unroll
    for (int r = 0; r < 16; r++) Oacc[c][r] = 0.f;

  float l_lane = 0.f;

  stage(t0, 0);
  stage((t0 + 1) & 63, 1);
  __syncthreads();                 // vmcnt(0): kbuf0/kbuf1 ready

#pragma unroll 1
  for (int lt = 0; lt < 64; ++lt) {
    const int ta = (lt + t0) & 63;

    // V frags FIRST (older than this iter's DMA in the vmcnt FIFO)
    const __hip_bfloat16* vb = vg + (size_t)(ta * 2 + kh) * 8192
                             + chh * 4096 + lane * 8;
    bf16x8 Vc[8];
#pragma unroll
    for (int c = 0; c < 4; c++) {
      Vc[2 * c]     = *(const bf16x8*)(vb + c * 1024);
      Vc[2 * c + 1] = *(const bf16x8*)(vb + c * 1024 + 512);
    }
    __builtin_amdgcn_sched_barrier(0);   // pin V-issue before DMA-issue

    if (lt < 62) stage((lt + 2 + t0) & 63, (lt + 2) % 3);

    // QK dual-chain: Sa (cs 0..3) + Sb (cs 4..7), summed in softmax
    const __hip_bfloat16* kbase = sm.u.kbuf[lt % 3] + kh * 4096 + lane * 8;
    f32x16 Sa = {}, Sb = {};
#pragma unroll
    for (int cs = 0; cs < 4; cs++) {
      bf16x8 kfa = *(const bf16x8*)(kbase + cs * 512);
      bf16x8 kfb = *(const bf16x8*)(kbase + (cs + 4) * 512);
      Sa = __builtin_amdgcn_mfma_f32_32x32x16_bf16(kfa, qf[cs],     Sa, 0, 0, 0);
      Sb = __builtin_amdgcn_mfma_f32_32x32x16_bf16(kfb, qf[cs + 4], Sb, 0, 0, 0);
    }

    unsigned p2[8];
    float lsub = 0.f;
#pragma unroll
    for (int i2 = 0; i2 < 8; i2++) {
      float a = exp2f(Sa[2 * i2]     + Sb[2 * i2]     - 64.0f);
      float c = exp2f(Sa[2 * i2 + 1] + Sb[2 * i2 + 1] - 64.0f);
      lsub += a + c;
      union { __hip_bfloat162 h; unsigned u; } cv;
      cv.h = __float22bfloat162_rn(float2{a, c});
      p2[i2] = cv.u;
    }
    l_lane += lsub;
    U4 f0, f1;
    f0.u[0] = p2[0]; f0.u[1] = p2[1]; f0.u[2] = p2[2]; f0.u[3] = p2[3];
    f1.u[0] = p2[4]; f1.u[1] = p2[5]; f1.u[2] = p2[6]; f1.u[3] = p2[7];
    const bf16x8 pf0 = f0.v, pf1 = f1.v;

#pragma unroll
    for (int c = 0; c < 4; c++) {
      Oacc[c] = __builtin_amdgcn_mfma_f32_32x32x16_bf16(Vc[2 * c],     pf0, Oacc[c], 0, 0, 0);
      Oacc[c] = __builtin_amdgcn_mfma_f32_32x32x16_bf16(Vc[2 * c + 1], pf1, Oacc[c], 0, 0, 0);
    }

    if (lt < 63) {
      __builtin_amdgcn_sched_barrier(0);
      __builtin_amdgcn_s_barrier();          // raw: NO vmcnt(0) drain
      __builtin_amdgcn_sched_barrier(0);
    }
  }

  float lfull = l_lane + __shfl_xor(l_lane, 32);
  if (lane < 32) sm.redu[w][l32] = lfull;
  __syncthreads();
  const int hb = lane >> 5;
  if (kh == 0) {
#pragma unroll
    for (int c = 0; c < 4; c++) {
#pragma unroll
      for (int r = 0; r < 16; r++) {
        int ch = (chh * 4 + c) * 32 + (r & 3) + 8 * (r >> 2) + 4 * hb;
        sm.u.ostage[ch][l32] = Oacc[c][r];
      }
    }
  }
  if (tid < 32) sm.rinv[tid] = 1.0f / (sm.redu[0][tid] + sm.redu[2][tid]);
  __syncthreads();
  if (kh == 1) {
#pragma unroll
    for (int c = 0; c < 4; c++) {
#pragma unroll
      for (int r = 0; r < 16; r++) {
        int ch = (chh * 4 + c) * 32 + (r & 3) + 8 * (r >> 2) + 4 * hb;
        sm.u.ostage[ch][l32] += Oacc[c][r];
      }
    }
  }
  __syncthreads();

  const float gmm = gammap[0];
  const int pix = tid & 31;
  const float ri = sm.rinv[pix];
#pragma unroll
  for (int j = 0; j < 32; ++j) {
    int ch = (tid >> 5) * 32 + j;
    size_t g = ((size_t)(b * 256 + ch)) * 4096 + n0 + pix;
    out[g] = gmm * sm.u.ostage[ch][pix] * ri + x_main[g];
  }
}

// ---------------------------------------------------------------------------
extern "C" void kernel_launch(void* const* d_in, const int* in_sizes, int n_in,
                              void* d_out, int out_size, void* d_ws, size_t ws_size,
                              hipStream_t stream) {
  (void)in_sizes; (void)n_in; (void)out_size; (void)ws_size;
  const float* x  = (const float*)d_in[0];
  const float* z  = (const float*)d_in[1];
  const float* Wq = (const float*)d_in[2];
  const float* bq = (const float*)d_in[3];
  const float* Wk = (const float*)d_in[4];
  const float* bk = (const float*)d_in[5];
  const float* Wv = (const float*)d_in[6];
  const float* bv = (const float*)d_in[7];
  const float* gm = (const float*)d_in[8];
  float* out = (float*)d_out;

  char* ws = (char*)d_ws;
  const size_t MB = 1024 * 1024;
  __hip_bfloat16* qp  = (__hip_bfloat16*)(ws);             // 4 MiB
  __hip_bfloat16* kp  = (__hip_bfloat16*)(ws + 4 * MB);    // 4 MiB
  __hip_bfloat16* vp  = (__hip_bfloat16*)(ws + 8 * MB);    // 8 MiB
  __hip_bfloat16* wfp = (__hip_bfloat16*)(ws + 16 * MB);   // 256 KiB

  wprep_kernel<<<16, 256, 0, stream>>>(Wq, Wk, Wv, wfp);
  projfused   <<<512, 512, 0, stream>>>(x, z, wfp, bq, bk, bv, qp, kp, vp);
  attn_kernel <<<512, 256, 0, stream>>>(qp, kp, vp, x, gm, out);
}

// Round 13
// 199.113 us; speedup vs baseline: 1.1417x; 1.0888x over previous
//
#include <hip/hip_runtime.h>
#include <hip/hip_bf16.h>

// CrossAttentionFusion: B=4, C=Cs=256, CI=128, H=W=64 -> N=M=4096
// R19 = recombination of measured winners:
//  - R18 ledger split: attn dual-chain QK REGRESSED (+24us) -> reverted to
//    R13 attn byte-identical (measured 106.5/108 across 3 runs).
//    projfused store-staging + dual-chain GAINED (~8.6us non-attn) -> kept.
//  - attn: R13 counted-vmcnt kbuf[3] body, single-chain QK (verbatim R15).
//  - projfused: R18 verbatim (LDS-staged coalesced q/k copy-out, 8-deep
//    dual MFMA chains, v direct stores).
//  - wprep: unchanged.
//
// qk-frag (Q B-op / K A-op), per 32-row group g:
//   addr = g*4096 + (ch>>4)*512 + ((ch>>3)&1)*256 + row*8 + (ch&7)
//   (K rows permuted: row = l32^12 if (l32>>2)&3 in {1,2} -> shuffle-free PV)
// V-frag (PV A-op), per 32-key group g: addr = g*8192 + (ch>>5)*1024
//   + ((key>>4)&1)*512 + ((key>>3)&1)*256 + (ch&31)*8 + (key&7)

typedef __bf16  bf16x8  __attribute__((ext_vector_type(8)));
typedef float   f32x16  __attribute__((ext_vector_type(16)));

#define LOG2E 1.4426950408889634f

union BF8 { __hip_bfloat162 h[4]; bf16x8 v; };
union U4  { unsigned u[4]; bf16x8 v; };

__device__ inline bf16x8 pack8(const float f[8]) {
  BF8 u;
#pragma unroll
  for (int i = 0; i < 4; i++)
    u.h[i] = __float22bfloat162_rn(float2{f[2 * i], f[2 * i + 1]});
  return u.v;
}

__device__ inline void dma16(const void* g, void* l) {
  __builtin_amdgcn_global_load_lds(
      (const __attribute__((address_space(1))) unsigned int*)g,
      (__attribute__((address_space(3))) unsigned int*)l, 16, 0, 0);
}

// ---------------------------------------------------------------------------
// wprep: W -> W-frag bf16 (16 blocks).
// ---------------------------------------------------------------------------
__global__ __launch_bounds__(256) void wprep_kernel(
    const float* __restrict__ Wq, const float* __restrict__ Wk,
    const float* __restrict__ Wv, __hip_bfloat16* __restrict__ wfr)
{
  const int base = blockIdx.x * 1024;
  const int tid = threadIdx.x;
#pragma unroll
  for (int i = 0; i < 4; i++) {
    int c = base + i * 256 + tid;          // [0, 16384)
    const float* Ws; __hip_bfloat16* dst; int rc;
    if (c < 4096)      { Ws = Wq; dst = wfr;          rc = c; }
    else if (c < 8192) { Ws = Wk; dst = wfr + 32768;  rc = c - 4096; }
    else               { Ws = Wv; dst = wfr + 65536;  rc = c - 8192; }
    int ot = rc >> 10, cs = (rc >> 6) & 15, rem = rc & 63;
    int hf = rem >> 5, l32 = rem & 31;
    const float* src = Ws + (ot * 32 + l32) * 256 + cs * 16 + hf * 8;
    float f[8];
#pragma unroll
    for (int j = 0; j < 8; j++) f[j] = src[j];
    *(bf16x8*)(dst + ot * 8192 + cs * 512 + hf * 256 + l32 * 8) = pack8(f);
  }
}

// ---------------------------------------------------------------------------
// projfused (R18 verbatim): stage input via LDS, pack to frag-LDS, dual-chain
// MFMA from LDS. q/k outputs staged in LDS -> contiguous bf16x8 stores;
// v direct. Grid 512: [0,256) q(x), [256,512) kv(z). 512 thr, 2 blocks/CU.
// ---------------------------------------------------------------------------
struct PFSmem {
  float stg[128 * 68];                     // 34,816 B; reused as bf16 out-stage
  alignas(16) __hip_bfloat16 frag[16384];  // 32,768 B frag layout
};

__global__ __launch_bounds__(512, 2) void projfused(
    const float* __restrict__ x, const float* __restrict__ z,
    const __hip_bfloat16* __restrict__ wfr,
    const float* __restrict__ bq, const float* __restrict__ bk,
    const float* __restrict__ bv,
    __hip_bfloat16* __restrict__ qp, __hip_bfloat16* __restrict__ kp,
    __hip_bfloat16* __restrict__ vp)
{
  __shared__ PFSmem sm;
  const int bi = blockIdx.x;
  const bool qmode = bi < 256;
  const int j2 = qmode ? bi : bi - 256;
  const int b = j2 >> 6, pc = j2 & 63;
  const float* in = qmode ? x : z;
  const size_t ib = (size_t)b * 256 * 4096 + pc * 64;

  const int tid = threadIdx.x, w = tid >> 6, lane = tid & 63,
            l32 = lane & 31, half = lane >> 5;
  const int pix4 = (tid & 15) * 4;

  // ---- stage/pack half 0 (ch 0..127 -> cs 0..7) ----
#pragma unroll
  for (int it = 0; it < 4; it++) {
    int ch = it * 32 + (tid >> 4);
    float4 v4 = *(const float4*)&in[ib + (size_t)ch * 4096 + pix4];
    *(float4*)&sm.stg[ch * 68 + pix4] = v4;
  }
  __syncthreads();
#pragma unroll
  for (int i = 0; i < 2; i++) {
    int c = i * 512 + tid;
    int grp = c >> 9, csl = (c >> 6) & 7, rem = c & 63;
    int hf = rem >> 5, lr = rem & 31;
    int chb = csl * 16 + hf * 8;
    float f[8];
#pragma unroll
    for (int j = 0; j < 8; j++) f[j] = sm.stg[(chb + j) * 68 + grp * 32 + lr];
    *(bf16x8*)(sm.frag + grp * 8192 + csl * 512 + hf * 256 + lr * 8) = pack8(f);
  }
  __syncthreads();

  // ---- stage/pack half 1 (ch 128..255 -> cs 8..15) ----
#pragma unroll
  for (int it = 0; it < 4; it++) {
    int ch = it * 32 + (tid >> 4);
    float4 v4 = *(const float4*)&in[ib + (size_t)(128 + ch) * 4096 + pix4];
    *(float4*)&sm.stg[ch * 68 + pix4] = v4;
  }
  __syncthreads();
#pragma unroll
  for (int i = 0; i < 2; i++) {
    int c = i * 512 + tid;
    int grp = c >> 9, csl = (c >> 6) & 7, rem = c & 63;
    int hf = rem >> 5, lr = rem & 31;
    int chb = csl * 16 + hf * 8;
    float f[8];
#pragma unroll
    for (int j = 0; j < 8; j++) f[j] = sm.stg[(chb + j) * 68 + grp * 32 + lr];
    *(bf16x8*)(sm.frag + grp * 8192 + (csl + 8) * 512 + hf * 256 + lr * 8) =
        pack8(f);
  }
  __syncthreads();                       // frag complete; stg now free

  const int t4 = (l32 >> 2) & 3;
  const int kperm = (t4 == 1 || t4 == 2) ? (l32 ^ 12) : l32;
  __hip_bfloat16* ostg = (__hip_bfloat16*)sm.stg;   // 16 KiB out-stage

  if (qmode) {
    const int ot = w >> 1, pg = w & 1;
    bf16x8 bfr[16];
#pragma unroll
    for (int cs = 0; cs < 16; cs++)
      bfr[cs] = *(const bf16x8*)(sm.frag + pg * 8192 + cs * 512 + lane * 8);
    const __hip_bfloat16* wp = wfr + ot * 8192 + lane * 8;
    bf16x8 wfg[16];
#pragma unroll
    for (int cs = 0; cs < 16; cs++) wfg[cs] = *(const bf16x8*)(wp + cs * 512);
    float bb[16];
#pragma unroll
    for (int r = 0; r < 16; r++)
      bb[r] = bq[ot * 32 + (r & 3) + 8 * (r >> 2) + 4 * half];
    f32x16 Oa = {}, Ob = {};
#pragma unroll
    for (int cs = 0; cs < 8; cs++) {     // two independent 8-deep chains
      Oa = __builtin_amdgcn_mfma_f32_32x32x16_bf16(wfg[cs],     bfr[cs],     Oa, 0, 0, 0);
      Ob = __builtin_amdgcn_mfma_f32_32x32x16_bf16(wfg[cs + 8], bfr[cs + 8], Ob, 0, 0, 0);
    }
    // stage in exact qp layout, then contiguous copy-out
#pragma unroll
    for (int r = 0; r < 16; r++) {
      int oc = ot * 32 + (r & 3) + 8 * (r >> 2) + 4 * half;
      ostg[pg * 4096 + (oc >> 4) * 512 + ((oc >> 3) & 1) * 256 + l32 * 8 +
           (oc & 7)] =
          __float2bfloat16((Oa[r] + Ob[r] + bb[r]) * LOG2E);
    }
    __syncthreads();
    __hip_bfloat16* qb = qp + ((size_t)(b * 128 + pc * 2)) * 4096;
    *(bf16x8*)(qb + tid * 8)        = *(const bf16x8*)(ostg + tid * 8);
    *(bf16x8*)(qb + 4096 + tid * 8) = *(const bf16x8*)(ostg + 4096 + tid * 8);
  } else {
    const int pg = w & 1;
    bf16x8 bfr[16];
#pragma unroll
    for (int cs = 0; cs < 16; cs++)
      bfr[cs] = *(const bf16x8*)(sm.frag + pg * 8192 + cs * 512 + lane * 8);
    const size_t pgg = (size_t)(b * 128 + pc * 2 + pg);

    // ---- job 0: K tile t = w>>1 (all waves do K first) ----
    {
      const int t = w >> 1;
      const __hip_bfloat16* wp = wfr + 32768 + t * 8192 + lane * 8;
      bf16x8 wfg[16];
#pragma unroll
      for (int cs = 0; cs < 16; cs++) wfg[cs] = *(const bf16x8*)(wp + cs * 512);
      float bb[16];
#pragma unroll
      for (int r = 0; r < 16; r++)
        bb[r] = bk[t * 32 + (r & 3) + 8 * (r >> 2) + 4 * half];
      f32x16 Oa = {}, Ob = {};
#pragma unroll
      for (int cs = 0; cs < 8; cs++) {
        Oa = __builtin_amdgcn_mfma_f32_32x32x16_bf16(wfg[cs],     bfr[cs],     Oa, 0, 0, 0);
        Ob = __builtin_amdgcn_mfma_f32_32x32x16_bf16(wfg[cs + 8], bfr[cs + 8], Ob, 0, 0, 0);
      }
#pragma unroll
      for (int r = 0; r < 16; r++) {
        int oc = t * 32 + (r & 3) + 8 * (r >> 2) + 4 * half;
        ostg[pg * 4096 + (oc >> 4) * 512 + ((oc >> 3) & 1) * 256 + kperm * 8 +
             (oc & 7)] = __float2bfloat16(Oa[r] + Ob[r] + bb[r]);
      }
    }
    __syncthreads();
    {
      __hip_bfloat16* kb = kp + ((size_t)(b * 128 + pc * 2)) * 4096;
      *(bf16x8*)(kb + tid * 8)        = *(const bf16x8*)(ostg + tid * 8);
      *(bf16x8*)(kb + 4096 + tid * 8) = *(const bf16x8*)(ostg + 4096 + tid * 8);
    }

    // ---- jobs 1,2: V tiles (direct stores — already 16-B-chunk granular) ----
#pragma unroll
    for (int jj = 1; jj < 3; jj++) {
      const int t = (w + jj * 8) >> 1;         // [4,12): V tile t-4
      const int tt = t - 4;
      const __hip_bfloat16* wp = wfr + 65536 + tt * 8192 + lane * 8;
      bf16x8 wfg[16];
#pragma unroll
      for (int cs = 0; cs < 16; cs++) wfg[cs] = *(const bf16x8*)(wp + cs * 512);
      float bb[16];
#pragma unroll
      for (int r = 0; r < 16; r++)
        bb[r] = bv[tt * 32 + (r & 3) + 8 * (r >> 2) + 4 * half];
      f32x16 Oa = {}, Ob = {};
#pragma unroll
      for (int cs = 0; cs < 8; cs++) {
        Oa = __builtin_amdgcn_mfma_f32_32x32x16_bf16(wfg[cs],     bfr[cs],     Oa, 0, 0, 0);
        Ob = __builtin_amdgcn_mfma_f32_32x32x16_bf16(wfg[cs + 8], bfr[cs + 8], Ob, 0, 0, 0);
      }
      __hip_bfloat16* vb = vp + pgg * 8192 + tt * 1024
          + (l32 >> 4) * 512 + ((l32 >> 3) & 1) * 256 + (l32 & 7);
#pragma unroll
      for (int r = 0; r < 16; r++) {
        int rr = (r & 3) + 8 * (r >> 2) + 4 * half;
        vb[rr * 8] = __float2bfloat16(Oa[r] + Ob[r] + bb[r]);
      }
    }
  }
}

// ---------------------------------------------------------------------------
// attn: R13 body VERBATIM (measured 106.5/108). Grid 512, 4 waves = (kh,chh).
// kbuf[3] counted-vmcnt K-DMA; raw s_barrier main loop; single-pass output.
// ---------------------------------------------------------------------------
struct AttnSmem {
  union {
    __hip_bfloat16 kbuf[3][8192];   // 3 x 16 KiB triple buffer
    float ostage[256][33];          // epilogue [ch][q], pad 33
  } u;
  float redu[4][32];
  float rinv[32];
};

__global__ __launch_bounds__(256, 3) void attn_kernel(
    const __hip_bfloat16* __restrict__ qv, const __hip_bfloat16* __restrict__ kv,
    const __hip_bfloat16* __restrict__ vv,
    const float* __restrict__ x_main, const float* __restrict__ gammap,
    float* __restrict__ out)
{
  __shared__ AttnSmem sm;
  const int i  = blockIdx.x;           // 512 blocks
  const int b  = (i & 7) >> 1;         // XCD-pair -> batch (K+V L2-resident)
  const int qt = ((i >> 3) << 1) | (i & 1);
  const int n0 = qt * 32;
  const int tid  = threadIdx.x;
  const int w    = tid >> 6, lane = tid & 63, l32 = lane & 31;
  const int kh   = w >> 1, chh = w & 1;
  const int t0   = qt & 63;            // stagger: de-correlate block streams

  bf16x8 qf[8];
  {
    const __hip_bfloat16* qb = qv + ((size_t)(b * 128 + qt)) * 4096 + lane * 8;
#pragma unroll
    for (int cs = 0; cs < 8; cs++) qf[cs] = *(const bf16x8*)(qb + cs * 512);
  }

  const __hip_bfloat16* kg = kv + (size_t)(b * 128) * 4096;
  const __hip_bfloat16* vg = vv + (size_t)(b * 128) * 8192;

  auto stage = [&](int ta, int par) {
    __hip_bfloat16* kd = sm.u.kbuf[par];
    const __hip_bfloat16* ksrc = kg + (size_t)ta * 8192 + lane * 8;
#pragma unroll
    for (int c = 0; c < 4; c++) {
      int ck = w * 4 + c;
      dma16(ksrc + ck * 512, kd + ck * 512 + lane * 8);
    }
  };

  f32x16 Oacc[4];
#pragma unroll
  for (int c = 0; c < 4; c++)
#pragma unroll
    for (int r = 0; r < 16; r++) Oacc[c][r] = 0.f;

  float l_lane = 0.f;

  stage(t0, 0);
  stage((t0 + 1) & 63, 1);
  __syncthreads();                 // vmcnt(0): kbuf0/kbuf1 ready

#pragma unroll 1
  for (int lt = 0; lt < 64; ++lt) {
    const int ta = (lt + t0) & 63;

    // V frags FIRST (older than this iter's DMA in the vmcnt FIFO)
    const __hip_bfloat16* vb = vg + (size_t)(ta * 2 + kh) * 8192
                             + chh * 4096 + lane * 8;
    bf16x8 Vc[8];
#pragma unroll
    for (int c = 0; c < 4; c++) {
      Vc[2 * c]     = *(const bf16x8*)(vb + c * 1024);
      Vc[2 * c + 1] = *(const bf16x8*)(vb + c * 1024 + 512);
    }
    __builtin_amdgcn_sched_barrier(0);   // pin V-issue before DMA-issue

    if (lt < 62) stage((lt + 2 + t0) & 63, (lt + 2) % 3);

    const __hip_bfloat16* kbase = sm.u.kbuf[lt % 3] + kh * 4096 + lane * 8;
    f32x16 S = {};
#pragma unroll
    for (int cs = 0; cs < 8; cs++) {
      bf16x8 kf = *(const bf16x8*)(kbase + cs * 512);
      S = __builtin_amdgcn_mfma_f32_32x32x16_bf16(kf, qf[cs], S, 0, 0, 0);
    }

    unsigned p2[8];
    float lsub = 0.f;
#pragma unroll
    for (int i2 = 0; i2 < 8; i2++) {
      float a = exp2f(S[2 * i2]     - 64.0f);
      float c = exp2f(S[2 * i2 + 1] - 64.0f);
      lsub += a + c;
      union { __hip_bfloat162 h; unsigned u; } cv;
      cv.h = __float22bfloat162_rn(float2{a, c});
      p2[i2] = cv.u;
    }
    l_lane += lsub;
    U4 f0, f1;
    f0.u[0] = p2[0]; f0.u[1] = p2[1]; f0.u[2] = p2[2]; f0.u[3] = p2[3];
    f1.u[0] = p2[4]; f1.u[1] = p2[5]; f1.u[2] = p2[6]; f1.u[3] = p2[7];
    const bf16x8 pf0 = f0.v, pf1 = f1.v;

#pragma unroll
    for (int c = 0; c < 4; c++) {
      Oacc[c] = __builtin_amdgcn_mfma_f32_32x32x16_bf16(Vc[2 * c],     pf0, Oacc[c], 0, 0, 0);
      Oacc[c] = __builtin_amdgcn_mfma_f32_32x32x16_bf16(Vc[2 * c + 1], pf1, Oacc[c], 0, 0, 0);
    }

    if (lt < 63) {
      __builtin_amdgcn_sched_barrier(0);
      __builtin_amdgcn_s_barrier();          // raw: NO vmcnt(0) drain
      __builtin_amdgcn_sched_barrier(0);
    }
  }

  float lfull = l_lane + __shfl_xor(l_lane, 32);
  if (lane < 32) sm.redu[w][l32] = lfull;
  __syncthreads();
  const int hb = lane >> 5;
  if (kh == 0) {
#pragma unroll
    for (int c = 0; c < 4; c++) {
#pragma unroll
      for (int r = 0; r < 16; r++) {
        int ch = (chh * 4 + c) * 32 + (r & 3) + 8 * (r >> 2) + 4 * hb;
        sm.u.ostage[ch][l32] = Oacc[c][r];
      }
    }
  }
  if (tid < 32) sm.rinv[tid] = 1.0f / (sm.redu[0][tid] + sm.redu[2][tid]);
  __syncthreads();
  if (kh == 1) {
#pragma unroll
    for (int c = 0; c < 4; c++) {
#pragma unroll
      for (int r = 0; r < 16; r++) {
        int ch = (chh * 4 + c) * 32 + (r & 3) + 8 * (r >> 2) + 4 * hb;
        sm.u.ostage[ch][l32] += Oacc[c][r];
      }
    }
  }
  __syncthreads();

  const float gmm = gammap[0];
  const int pix = tid & 31;
  const float ri = sm.rinv[pix];
#pragma unroll
  for (int j = 0; j < 32; ++j) {
    int ch = (tid >> 5) * 32 + j;
    size_t g = ((size_t)(b * 256 + ch)) * 4096 + n0 + pix;
    out[g] = gmm * sm.u.ostage[ch][pix] * ri + x_main[g];
  }
}

// ---------------------------------------------------------------------------
extern "C" void kernel_launch(void* const* d_in, const int* in_sizes, int n_in,
                              void* d_out, int out_size, void* d_ws, size_t ws_size,
                              hipStream_t stream) {
  (void)in_sizes; (void)n_in; (void)out_size; (void)ws_size;
  const float* x  = (const float*)d_in[0];
  const float* z  = (const float*)d_in[1];
  const float* Wq = (const float*)d_in[2];
  const float* bq = (const float*)d_in[3];
  const float* Wk = (const float*)d_in[4];
  const float* bk = (const float*)d_in[5];
  const float* Wv = (const float*)d_in[6];
  const float* bv = (const float*)d_in[7];
  const float* gm = (const float*)d_in[8];
  float* out = (float*)d_out;

  char* ws = (char*)d_ws;
  const size_t MB = 1024 * 1024;
  __hip_bfloat16* qp  = (__hip_bfloat16*)(ws);             // 4 MiB
  __hip_bfloat16* kp  = (__hip_bfloat16*)(ws + 4 * MB);    // 4 MiB
  __hip_bfloat16* vp  = (__hip_bfloat16*)(ws + 8 * MB);    // 8 MiB
  __hip_bfloat16* wfp = (__hip_bfloat16*)(ws + 16 * MB);   // 256 KiB

  wprep_kernel<<<16, 256, 0, stream>>>(Wq, Wk, Wv, wfp);
  projfused   <<<512, 512, 0, stream>>>(x, z, wfp, bq, bk, bv, qp, kp, vp);
  attn_kernel <<<512, 256, 0, stream>>>(qp, kp, vp, x, gm, out);
}